// Round 10
// baseline (156.722 us; speedup 1.0000x reference)
//
#include <hip/hip_runtime.h>

typedef __bf16 bf16;
typedef __bf16 bf16x8 __attribute__((ext_vector_type(8)));
typedef float  f32x4  __attribute__((ext_vector_type(4)));

#define MFMA(a, b, c) __builtin_amdgcn_mfma_f32_16x16x32_bf16((a), (b), (c), 0, 0, 0)

static constexpr int B_   = 2;
static constexpr int T_   = 2048;
static constexpr int D_   = 1024;
static constexpr int NH_  = 16;
static constexpr int HD_  = 64;
static constexpr int WIN_ = 256;
static constexpr int M_   = B_ * T_;          // 4096
static constexpr int NQKV = D_ + 2 * HD_;     // 1152

// async global->LDS, 16B per lane; global addr per-lane, LDS dst wave-uniform
// base + lane*16 [m97/m104-verified]
__device__ __forceinline__ void gld_lds16(const bf16* g, bf16* l) {
  __builtin_amdgcn_global_load_lds(
      (const __attribute__((address_space(1))) void*)g,
      (__attribute__((address_space(3))) void*)l, 16, 0, 0);
}

// ---------------------------------------------------------------------------
// Fused fp32->bf16 conversion of all 6 inputs. Wq/Wk/Wv -> Wqkv[1152][1024].
// ---------------------------------------------------------------------------
__global__ __launch_bounds__(256) void conv_all(
    const float* __restrict__ x,  const float* __restrict__ wq,
    const float* __restrict__ wk, const float* __restrict__ wv,
    const float* __restrict__ wf, const float* __restrict__ bv,
    bf16* __restrict__ xc, bf16* __restrict__ wqkv,
    bf16* __restrict__ wfc, bf16* __restrict__ bfc) {
  const long i = (long)(blockIdx.x * 256 + threadIdx.x) * 4;
  const float* src; bf16* dst; long off;
  if      (i < 4194304L) { src = x;  dst = xc;              off = 0; }
  else if (i < 5242880L) { src = wq; dst = wqkv;            off = 4194304L; }
  else if (i < 5308416L) { src = wk; dst = wqkv + 1048576L; off = 5242880L; }
  else if (i < 5373952L) { src = wv; dst = wqkv + 1114112L; off = 5308416L; }
  else if (i < 6422528L) { src = wf; dst = wfc;             off = 5373952L; }
  else if (i < 6423552L) { src = bv; dst = bfc;             off = 6422528L; }
  else return;
  const long j = i - off;
  const float4 v = *(const float4*)(src + j);
  bf16 o[4] = {(bf16)v.x, (bf16)v.y, (bf16)v.z, (bf16)v.w};
  *(uint2*)(dst + j) = *(const uint2*)o;
}

// ---------------------------------------------------------------------------
// GEMM, tile M=64 x N=128, BK=64 (r6/r8-benched structure; BK=128 regressed,
// r7 + m132 precedent). 256 thr = 4 waves; wave = 32x64 (2x4 MFMA).
// C[M,N] = A[M,K] @ B[N,K]^T.
// EPI=1: QKV split (q SCALED by 0.125 / k / vT transposed). EPI=2: fp32+bias.
// ---------------------------------------------------------------------------
template <int EPI>
__global__ __launch_bounds__(256) void gemm64x128(
    const bf16* __restrict__ A, const bf16* __restrict__ Bw,
    void* __restrict__ Cout, const bf16* __restrict__ bias,
    bf16* __restrict__ kb, bf16* __restrict__ vT, int N, int K) {
  __shared__ __align__(16) bf16 As[64 * 64];    //  8 KB
  __shared__ __align__(16) bf16 Bs[128 * 64];   // 16 KB

  const int tid  = threadIdx.x;
  const int w    = tid >> 6;
  const int lane = tid & 63;
  const int quad = lane >> 4;
  const int l16  = lane & 15;
  const int wm   = w & 1;   // row half (32 rows)
  const int wn   = w >> 1;  // col half (64 cols)
  const int m0   = blockIdx.x * 64;
  const int n0   = blockIdx.y * 128;
  const int lrow = lane >> 3;        // 0..7
  const int lcol = (lane & 7) * 8;   // 0..56

  f32x4 acc[2][4] = {};

  for (int k0 = 0; k0 < K; k0 += 64) {
    __syncthreads();
    // 24 gld_lds16 insts: 8 for As (64 rows), 16 for Bs (128 rows); 6/wave
#pragma unroll
    for (int t = 0; t < 6; ++t) {
      const int inst = w * 6 + t;  // wave-uniform
      if (inst < 8) {
        gld_lds16(&A[(size_t)(m0 + inst * 8 + lrow) * K + k0 + lcol],
                  &As[inst * 512]);
      } else {
        const int bi = inst - 8;
        gld_lds16(&Bw[(size_t)(n0 + bi * 8 + lrow) * K + k0 + lcol],
                  &Bs[bi * 512]);
      }
    }
    __syncthreads();
#pragma unroll
    for (int kk = 0; kk < 64; kk += 32) {
      bf16x8 a[2], b[4];
#pragma unroll
      for (int i = 0; i < 2; ++i)
        a[i] = *(const bf16x8*)&As[(wm * 32 + i * 16 + l16) * 64 + kk + quad * 8];
#pragma unroll
      for (int j = 0; j < 4; ++j)
        b[j] = *(const bf16x8*)&Bs[(wn * 64 + j * 16 + l16) * 64 + kk + quad * 8];
#pragma unroll
      for (int i = 0; i < 2; ++i)
#pragma unroll
        for (int j = 0; j < 4; ++j) acc[i][j] = MFMA(a[i], b[j], acc[i][j]);
    }
  }

  // epilogue: C/D layout col=l16, row=quad*4+r (m89-verified)
#pragma unroll
  for (int i = 0; i < 2; ++i) {
#pragma unroll
    for (int j = 0; j < 4; ++j) {
      const int col     = n0 + wn * 64 + j * 16 + l16;
      const int rowbase = m0 + wm * 32 + i * 16 + quad * 4;
      if (EPI == 1) {
        if (col < D_) {
          bf16* qb = (bf16*)Cout;
#pragma unroll
          for (int r = 0; r < 4; ++r)  // fold softmax scale 1/sqrt(64) into q
            qb[(size_t)(rowbase + r) * D_ + col] = (bf16)(acc[i][j][r] * 0.125f);
        } else if (col < D_ + HD_) {
#pragma unroll
          for (int r = 0; r < 4; ++r)
            kb[(size_t)(rowbase + r) * HD_ + (col - D_)] = (bf16)acc[i][j][r];
        } else {
          bf16 o[4] = {(bf16)acc[i][j][0], (bf16)acc[i][j][1],
                       (bf16)acc[i][j][2], (bf16)acc[i][j][3]};
          *(uint2*)&vT[(size_t)(col - D_ - HD_) * M_ + rowbase] = *(const uint2*)o;
        }
      } else {
        float* outp = (float*)Cout;
        const float bvv = (float)bias[col];
#pragma unroll
        for (int r = 0; r < 4; ++r)
          outp[(size_t)(rowbase + r) * D_ + col] = acc[i][j][r] + bvv;
      }
    }
  }
}

// ---------------------------------------------------------------------------
// Windowed attention (MQA), Q-tile = 128, 128 threads = 2 WAVES, each wave
// computes a 64t x 64s tile (fragment-reuse restructure: in-loop LDS reads
// per MFMA drop 0.75 -> 0.375, total b128 reads halve vs r9).
// - Q fragments HOISTED to registers (loop-invariant, 32 VGPRs).
// - S^T trick kept: MFMA(A=K,B=Q) -> C/D col=t,row=s -> b64 Ps stores.
// - PV operand swap: MFMA(A=Vt,B=Ps) -> C/D col=t,row=h -> h contiguous in
//   regs: 16x b64 output stores (was 64x b16), l[t] = lane's own l_part
//   (LDS redistribute deleted).
// - K/V double-buffered via global_load_lds; 2 barriers/iter.
// LDS 66 KB -> 2 blocks/CU (grid 512 = 2/CU). Un-normalized softmax
// (exp(min(logit,30)), masked->0): NaN-free. In-place q/o safe.
// ---------------------------------------------------------------------------
__global__ __launch_bounds__(128, 1) void attn_win128(
    const bf16* __restrict__ q, const bf16* __restrict__ k,
    const bf16* __restrict__ vT, bf16* __restrict__ o) {
  __shared__ __align__(16) bf16 Qs[128 * 64];     // 16 KB
  __shared__ __align__(16) bf16 Ks[2][64 * 64];   // 16 KB
  __shared__ __align__(16) bf16 Vt[2][64 * 64];   // 16 KB [h][s]
  __shared__ __align__(16) bf16 Ps[128 * 72];     // 18 KB padded [t][s]

  const int tid  = threadIdx.x;
  const int w    = tid >> 6;         // 0..1
  const int lane = tid & 63;
  const int quad = lane >> 4;
  const int l16  = lane & 15;
  const int lrow = lane >> 3;        // 0..7
  const int lcol = (lane & 7) * 8;   // 0..56

  const int t0 = blockIdx.x * 128;
  const int n  = blockIdx.y;
  const int b  = blockIdx.z;

  // stage Q tile (128 rows x 64): 16 insts, 8 per wave
#pragma unroll
  for (int t = 0; t < 8; ++t) {
    const int inst = w * 8 + t;
    gld_lds16(&q[((size_t)(b * T_ + t0 + inst * 8 + lrow)) * D_ + n * HD_ + lcol],
              &Qs[inst * 512]);
  }

  auto stageKV = [&](int st, int pb) {
#pragma unroll
    for (int t = 0; t < 4; ++t) {
      const int inst = w * 4 + t;
      gld_lds16(&k[((size_t)(b * T_ + st + inst * 8 + lrow)) * HD_ + lcol],
                &Ks[pb][inst * 512]);
      gld_lds16(&vT[(size_t)(inst * 8 + lrow) * M_ + b * T_ + st + lcol],
                &Vt[pb][inst * 512]);
    }
  };

  const int st_lo = (t0 - WIN_ > 0) ? t0 - WIN_ : 0;
  const int st_hi = (t0 + WIN_ + 64 < T_ - 64) ? t0 + WIN_ + 64 : T_ - 64;

  stageKV(st_lo, 0);
  __syncthreads();  // Q + KV0 staged & drained

  // hoisted Q fragments: B-frag rows t = w*64 + tt*16 + l16, k = kc*32+quad*8
  bf16x8 bq[4][2];
#pragma unroll
  for (int tt = 0; tt < 4; ++tt)
#pragma unroll
    for (int kc = 0; kc < 2; ++kc)
      bq[tt][kc] =
          *(const bf16x8*)&Qs[(w * 64 + tt * 16 + l16) * 64 + kc * 32 + quad * 8];

  int pb = 0;
  f32x4 o_acc[4][4] = {};          // [nt=h-tile][tt=t-tile]
  float l_part[4] = {};            // per-t partials, t = t0+w*64+tt*16+l16

  for (int st = st_lo; st <= st_hi; st += 64) {
    if (st + 64 <= st_hi) stageKV(st + 64, pb ^ 1);  // overlapped prefetch

    // S^T = K Q^T : D col=t, row=s ; wave: 64 s x 64 t
    f32x4 sacc[4][4] = {};  // [stile][tt]
#pragma unroll
    for (int kc = 0; kc < 2; ++kc) {
      bf16x8 ak[4];
#pragma unroll
      for (int stile = 0; stile < 4; ++stile)
        ak[stile] =
            *(const bf16x8*)&Ks[pb][(stile * 16 + l16) * 64 + kc * 32 + quad * 8];
#pragma unroll
      for (int stile = 0; stile < 4; ++stile)
#pragma unroll
        for (int tt = 0; tt < 4; ++tt)
          sacc[stile][tt] = MFMA(ak[stile], bq[tt][kc], sacc[stile][tt]);
    }

    // softmax numerators; lane: t = w*64+tt*16+l16, s = st+stile*16+quad*4+r
    const int off_t = st - t0;
    const bool need_mask =
        (off_t < w * 64 - 193) || (off_t > w * 64 + 193);
    if (!need_mask) {
#pragma unroll
      for (int tt = 0; tt < 4; ++tt) {
#pragma unroll
        for (int stile = 0; stile < 4; ++stile) {
          bf16 pk[4];
          float psum = 0.0f;
#pragma unroll
          for (int r = 0; r < 4; ++r) {
            const float p = __expf(fminf(sacc[stile][tt][r], 30.0f));
            psum += p;
            pk[r] = (bf16)p;
          }
          l_part[tt] += psum;
          *(uint2*)&Ps[(w * 64 + tt * 16 + l16) * 72 + stile * 16 + quad * 4] =
              *(const uint2*)pk;
        }
      }
    } else {
#pragma unroll
      for (int tt = 0; tt < 4; ++tt) {
        const int t = t0 + w * 64 + tt * 16 + l16;
#pragma unroll
        for (int stile = 0; stile < 4; ++stile) {
          bf16 pk[4];
          float psum = 0.0f;
#pragma unroll
          for (int r = 0; r < 4; ++r) {
            const int s = st + stile * 16 + quad * 4 + r;
            const int d = t - s;
            const float p = (d > WIN_ || d < -WIN_)
                                ? 0.0f
                                : __expf(fminf(sacc[stile][tt][r], 30.0f));
            psum += p;
            pk[r] = (bf16)p;
          }
          l_part[tt] += psum;
          *(uint2*)&Ps[(w * 64 + tt * 16 + l16) * 72 + stile * 16 + quad * 4] =
              *(const uint2*)pk;
        }
      }
    }
    __syncthreads();  // B1: Ps visible; prefetch drained (overlapped)

    // O^T tile: MFMA(A=Vt rows h, B=Ps rows t) -> D col=t, row=h
#pragma unroll
    for (int kc = 0; kc < 2; ++kc) {
      bf16x8 ap[4], bv[4];
#pragma unroll
      for (int tt = 0; tt < 4; ++tt)
        ap[tt] =
            *(const bf16x8*)&Ps[(w * 64 + tt * 16 + l16) * 72 + kc * 32 + quad * 8];
#pragma unroll
      for (int nt = 0; nt < 4; ++nt)
        bv[nt] =
            *(const bf16x8*)&Vt[pb][(nt * 16 + l16) * 64 + kc * 32 + quad * 8];
#pragma unroll
      for (int nt = 0; nt < 4; ++nt)
#pragma unroll
        for (int tt = 0; tt < 4; ++tt)
          o_acc[nt][tt] = MFMA(bv[nt], ap[tt], o_acc[nt][tt]);
    }
    __syncthreads();  // B2: PV reads done before next prefetch/softmax write
    pb ^= 1;
  }

  // l[t]: reduce the 4 quads' partials (lane keeps its own t = tt*16+l16)
#pragma unroll
  for (int tt = 0; tt < 4; ++tt) {
    l_part[tt] += __shfl_xor(l_part[tt], 16);
    l_part[tt] += __shfl_xor(l_part[tt], 32);
  }

  // store: element (t = t0+w*64+tt*16+l16, h = nt*16+quad*4+r) -> b64 stores
#pragma unroll
  for (int tt = 0; tt < 4; ++tt) {
    const float lr = l_part[tt] + 1e-30f;
    const int t = t0 + w * 64 + tt * 16 + l16;
#pragma unroll
    for (int nt = 0; nt < 4; ++nt) {
      bf16 ov[4];
#pragma unroll
      for (int r = 0; r < 4; ++r) ov[r] = (bf16)(o_acc[nt][tt][r] / lr);
      *(uint2*)&o[((size_t)(b * T_ + t)) * D_ + n * HD_ + nt * 16 + quad * 4] =
          *(const uint2*)ov;
    }
  }
}

// ---------------------------------------------------------------------------
extern "C" void kernel_launch(void* const* d_in, const int* in_sizes, int n_in,
                              void* d_out, int out_size, void* d_ws, size_t ws_size,
                              hipStream_t stream) {
  float* out = (float*)d_out;  // reference output dtype is float32

  bf16* xc   = (bf16*)d_ws;                   // 4096 x 1024
  bf16* wqkv = xc   + (size_t)M_ * D_;        // 1152 x 1024
  bf16* wfc  = wqkv + (size_t)NQKV * D_;      // 1024 x 1024
  bf16* bfc  = wfc  + (size_t)D_ * D_;        // 1024
  bf16* qb   = bfc  + D_;                     // 4096 x 1024 (attn out in-place)
  bf16* kb   = qb   + (size_t)M_ * D_;        // 4096 x 64
  bf16* vT   = kb   + (size_t)M_ * HD_;       // 64 x 4096 (transposed)

  dim3 blk(256);
  conv_all<<<dim3((6423552 / 4 + 255) / 256), blk, 0, stream>>>(
      (const float*)d_in[0], (const float*)d_in[1], (const float*)d_in[2],
      (const float*)d_in[3], (const float*)d_in[4], (const float*)d_in[5],
      xc, wqkv, wfc, bfc);

  gemm64x128<1><<<dim3(M_ / 64, NQKV / 128), blk, 0, stream>>>(
      xc, wqkv, (void*)qb, nullptr, kb, vT, NQKV, D_);

  attn_win128<<<dim3(T_ / 128, NH_, B_), dim3(128), 0, stream>>>(qb, kb, vT, qb);

  gemm64x128<2><<<dim3(M_ / 64, D_ / 128), blk, 0, stream>>>(
      qb, wfc, (void*)out, bfc, nullptr, nullptr, D_, D_);
}